// Round 3
// baseline (40811.380 us; speedup 1.0000x reference)
//
#include <hip/hip_runtime.h>
#include <hip/hip_cooperative_groups.h>

namespace cg = cooperative_groups;

#define DI __device__ __forceinline__

using f32x4  = __attribute__((ext_vector_type(4))) float;
using u16x8  = __attribute__((ext_vector_type(8))) unsigned short;
using bf16x8 = __attribute__((ext_vector_type(8))) __bf16;

constexpr int BB = 64;    // batch
constexpr int TT = 512;   // time
constexpr int II = 512;   // input dim
constexpr int HH = 1024;  // hidden
constexpr int G4 = 4096;  // 4*H
constexpr int OO = 512;   // output dim

DI unsigned short f2bf(float f) {
    unsigned int u = __builtin_bit_cast(unsigned int, f);
    u += 0x7fffu + ((u >> 16) & 1u);   // RNE
    return (unsigned short)(u >> 16);
}
DI float bf2f(unsigned short h) {
    unsigned int u = ((unsigned int)h) << 16;
    return __builtin_bit_cast(float, u);
}
DI f32x4 mfma_bf16(u16x8 a, u16x8 b, f32x4 c) {
    return __builtin_amdgcn_mfma_f32_16x16x32_bf16(
        __builtin_bit_cast(bf16x8, a), __builtin_bit_cast(bf16x8, b), c, 0, 0, 0);
}
DI float sigm(float x) { return 1.f / (1.f + __expf(-x)); }
DI float tanh_f(float x) { return 2.f / (1.f + __expf(-2.f * x)) - 1.f; }

// ---------------------------------------------------------------- cvt fp32->bf16
__global__ __launch_bounds__(256) void cvt4(const float4* __restrict__ in,
                                            ushort4* __restrict__ out, int n4) {
    int i = blockIdx.x * 256 + threadIdx.x;
    if (i < n4) {
        float4 v = in[i];
        ushort4 o;
        o.x = f2bf(v.x); o.y = f2bf(v.y); o.z = f2bf(v.z); o.w = f2bf(v.w);
        out[i] = o;
    }
}

// ---------------------------------------------------------------- xproj GEMM
__global__ __launch_bounds__(256)
void gemm_xproj(const float* __restrict__ seq, const ushort* __restrict__ Wih,
                const float* __restrict__ bih, const float* __restrict__ bhh,
                ushort* __restrict__ xp, int lgTc, int t0) {
    __shared__ ushort As[128 * 40];
    __shared__ ushort Bs[128 * 40];
    const int tid  = threadIdx.x;
    const int lane = tid & 63, wave = tid >> 6;
    const int wm = (wave >> 1) * 64, wn = (wave & 1) * 64;
    const int bn = blockIdx.x * 128;
    const int bm = blockIdx.y * 128;
    const int l15 = lane & 15, l4 = lane >> 4;

    const int srow = tid >> 1, shalf = tid & 1;
    const int rloc = bm + srow;
    const int bIdx = rloc >> lgTc, tl = rloc & ((1 << lgTc) - 1);
    const float*  gA = seq + ((size_t)bIdx * TT + t0 + tl) * II + shalf * 16;
    const ushort* gB = Wih + (size_t)(bn + srow) * II + shalf * 16;
    ushort* sA = &As[srow * 40 + shalf * 16];
    ushort* sB = &Bs[srow * 40 + shalf * 16];

    f32x4 acc[4][4] = {};
    alignas(16) float  raf[16];
    alignas(16) ushort rbf[16];

#define LOAD_A(kk)                                                        \
    { const float* p = gA + (kk) * 32;                                    \
      *(float4*)(raf + 0)  = *(const float4*)(p + 0);                     \
      *(float4*)(raf + 4)  = *(const float4*)(p + 4);                     \
      *(float4*)(raf + 8)  = *(const float4*)(p + 8);                     \
      *(float4*)(raf + 12) = *(const float4*)(p + 12); }
#define LOAD_B(kk)                                                        \
    { const ushort* p = gB + (kk) * 32;                                   \
      *(u16x8*)(rbf + 0) = *(const u16x8*)(p + 0);                        \
      *(u16x8*)(rbf + 8) = *(const u16x8*)(p + 8); }

    LOAD_A(0); LOAD_B(0);
    const int nk = II / 32;
    for (int kk = 0; kk < nk; ++kk) {
        __syncthreads();
        alignas(16) ushort cv[16];
#pragma unroll
        for (int j = 0; j < 16; ++j) cv[j] = f2bf(raf[j]);
        *(u16x8*)(sA + 0) = *(u16x8*)(cv + 0);
        *(u16x8*)(sA + 8) = *(u16x8*)(cv + 8);
        *(u16x8*)(sB + 0) = *(u16x8*)(rbf + 0);
        *(u16x8*)(sB + 8) = *(u16x8*)(rbf + 8);
        __syncthreads();
        if (kk + 1 < nk) { LOAD_A(kk + 1); LOAD_B(kk + 1); }
        u16x8 af[4], bfr[4];
#pragma unroll
        for (int i = 0; i < 4; ++i) {
            af[i]  = *(const u16x8*)&As[(wm + i * 16 + l15) * 40 + l4 * 8];
            bfr[i] = *(const u16x8*)&Bs[(wn + i * 16 + l15) * 40 + l4 * 8];
        }
#pragma unroll
        for (int mi = 0; mi < 4; ++mi)
#pragma unroll
            for (int ni = 0; ni < 4; ++ni)
                acc[mi][ni] = mfma_bf16(af[mi], bfr[ni], acc[mi][ni]);
    }
#undef LOAD_A
#undef LOAD_B

#pragma unroll
    for (int mi = 0; mi < 4; ++mi) {
#pragma unroll
        for (int ni = 0; ni < 4; ++ni) {
            const int row = bm + wm + mi * 16 + l4 * 4;
            const int col = bn + wn + ni * 16 + l15;
            const float bsum = bih[col] + bhh[col];
#pragma unroll
            for (int r = 0; r < 4; ++r)
                xp[(size_t)(row + r) * G4 + col] = f2bf(acc[mi][ni][r] + bsum);
        }
    }
}

// ---------------------------------------------------------------- output GEMM
__global__ __launch_bounds__(256)
void gemm_out(const ushort* __restrict__ hsC, const ushort* __restrict__ Wout,
              const float* __restrict__ bout, float* __restrict__ out,
              int lgTc, int t0) {
    __shared__ ushort As[128 * 40];
    __shared__ ushort Bs[128 * 40];
    const int tid  = threadIdx.x;
    const int lane = tid & 63, wave = tid >> 6;
    const int wm = (wave >> 1) * 64, wn = (wave & 1) * 64;
    const int bn = blockIdx.x * 128;
    const int bm = blockIdx.y * 128;
    const int l15 = lane & 15, l4 = lane >> 4;

    const int srow = tid >> 1, shalf = tid & 1;
    const ushort* gA = hsC  + (size_t)(bm + srow) * HH + shalf * 16;
    const ushort* gB = Wout + (size_t)(bn + srow) * HH + shalf * 16;
    ushort* sA = &As[srow * 40 + shalf * 16];
    ushort* sB = &Bs[srow * 40 + shalf * 16];

    f32x4 acc[4][4] = {};
    u16x8 ra0 = *(const u16x8*)(gA + 0), ra1 = *(const u16x8*)(gA + 8);
    u16x8 rb0 = *(const u16x8*)(gB + 0), rb1 = *(const u16x8*)(gB + 8);

    const int nk = HH / 32;
    for (int kk = 0; kk < nk; ++kk) {
        __syncthreads();
        *(u16x8*)(sA + 0) = ra0; *(u16x8*)(sA + 8) = ra1;
        *(u16x8*)(sB + 0) = rb0; *(u16x8*)(sB + 8) = rb1;
        __syncthreads();
        if (kk + 1 < nk) {
            const ushort* pa = gA + (kk + 1) * 32;
            const ushort* pb = gB + (kk + 1) * 32;
            ra0 = *(const u16x8*)(pa + 0); ra1 = *(const u16x8*)(pa + 8);
            rb0 = *(const u16x8*)(pb + 0); rb1 = *(const u16x8*)(pb + 8);
        }
        u16x8 af[4], bfr[4];
#pragma unroll
        for (int i = 0; i < 4; ++i) {
            af[i]  = *(const u16x8*)&As[(wm + i * 16 + l15) * 40 + l4 * 8];
            bfr[i] = *(const u16x8*)&Bs[(wn + i * 16 + l15) * 40 + l4 * 8];
        }
#pragma unroll
        for (int mi = 0; mi < 4; ++mi)
#pragma unroll
            for (int ni = 0; ni < 4; ++ni)
                acc[mi][ni] = mfma_bf16(af[mi], bfr[ni], acc[mi][ni]);
    }

    const int Tcm1 = (1 << lgTc) - 1;
#pragma unroll
    for (int mi = 0; mi < 4; ++mi) {
#pragma unroll
        for (int ni = 0; ni < 4; ++ni) {
            const int row = bm + wm + mi * 16 + l4 * 4;
            const int col = bn + wn + ni * 16 + l15;
            const float bs = bout[col];
#pragma unroll
            for (int r = 0; r < 4; ++r) {
                const int rl = row + r;
                const int bIdx = rl >> lgTc, tl = rl & Tcm1;
                out[((size_t)bIdx * TT + t0 + tl) * OO + col] = acc[mi][ni][r] + bs;
            }
        }
    }
}

// ---------------------------------------------------------------- persistent scan
// 256 blocks = 4 batch-groups (16 batches) x 64 j-slices (16 cols x 4 gates).
// Whh slice (64 rows x 1024) lives in LDS in MFMA fragment layout.
// Wave w handles j-sub [w*4, w*4+4) x 4 gates (N=16), all 16 batches (M=16).
__global__ __launch_bounds__(256, 1)
void lstm_scan(const ushort* __restrict__ Whh,  // [4096,1024] bf16
               const ushort* __restrict__ xp,   // [B*Tc,4096] bf16 (biases folded)
               ushort* __restrict__ hsC,        // [B*Tc,1024] bf16
               ushort* __restrict__ hbuf,       // [2][64*1024] bf16 ping-pong
               float* __restrict__ cst,         // [64*1024] fp32
               int Tc, int t0) {
    __shared__ ushort Ws[64 * 1024];   // 128 KB, fragment layout
    const int tid  = threadIdx.x;
    const int lane = tid & 63, wave = tid >> 6;
    const int l15 = lane & 15, l4 = lane >> 4;
    const int g = l15 >> 2, jj = l15 & 3;
    const int bx = blockIdx.x;
    const int bg = bx >> 6, js = bx & 63;
    const int j0 = js * 16;

    // ---- stage Whh slice -> LDS fragment layout (once per launch)
    {
        const int r64 = tid >> 2, q = tid & 3;
        const int wv = r64 >> 4, c = r64 & 15;
        const int gg = c >> 2, j2 = c & 3;
        const size_t grow = (size_t)(gg * HH + j0 + wv * 4 + j2) * HH;
#pragma unroll 4
        for (int seg = 0; seg < 32; ++seg) {
            u16x8 v = *(const u16x8*)(Whh + grow + seg * 32 + q * 8);
            *(u16x8*)&Ws[(((wv * 32 + seg) * 4 + q) * 16 + c) * 8] = v;
        }
    }
    __syncthreads();

    cg::grid_group grid = cg::this_grid();

    const int bglob = bg * 16 + l4 * 4;        // + r
    const int jcol  = j0 + wave * 4 + jj;      // this lane's hidden column
    const ushort* wsbase = &Ws[(wave * 32 * 64 + lane) * 8];

    float cr[4];
    if (t0 > 0) {
#pragma unroll
        for (int r = 0; r < 4; ++r) cr[r] = cst[(size_t)(bglob + r) * HH + jcol];
    } else {
#pragma unroll
        for (int r = 0; r < 4; ++r) cr[r] = 0.f;
    }

    for (int tl = 0; tl < Tc; ++tl) {
        const int t = t0 + tl;

        // xp preacts for this lane's gate (issued early, used after K-loop)
        float xg[4];
#pragma unroll
        for (int r = 0; r < 4; ++r)
            xg[r] = bf2f(xp[((size_t)(bglob + r) * Tc + tl) * G4 + g * HH + jcol]);

        f32x4 ac0 = {}, ac1 = {};
        if (t > 0) {
            const ushort* hprev = hbuf + (size_t)((t - 1) & 1) * (BB * HH);
            const ushort* gA = hprev + (size_t)(bg * 16 + l15) * HH + l4 * 8;
            u16x8 apf[4];
#pragma unroll
            for (int p = 0; p < 4; ++p) apf[p] = *(const u16x8*)(gA + p * 32);
#pragma unroll
            for (int kk = 0; kk < 32; ++kk) {
                u16x8 a = apf[kk & 3];
                if (kk + 4 < 32) apf[kk & 3] = *(const u16x8*)(gA + (kk + 4) * 32);
                u16x8 b = *(const u16x8*)(wsbase + (size_t)kk * 64 * 8);
                if (kk & 1) ac1 = mfma_bf16(a, b, ac1);
                else        ac0 = mfma_bf16(a, b, ac0);
            }
        }

        // per-lane preact (own gate), then gather all 4 gates via shuffles
        f32x4 s;
#pragma unroll
        for (int r = 0; r < 4; ++r) s[r] = ac0[r] + ac1[r] + xg[r];

        float pre[4][4];
#pragma unroll
        for (int gp = 0; gp < 4; ++gp) {
            const int src = (l4 << 4) + gp * 4 + jj;
#pragma unroll
            for (int r = 0; r < 4; ++r) pre[gp][r] = __shfl(s[r], src, 64);
        }

        unsigned short hnew[4];
#pragma unroll
        for (int r = 0; r < 4; ++r) {
            float ig = sigm(pre[0][r]);
            float fg = sigm(pre[1][r]);
            float gv = tanh_f(pre[2][r]);
            float og = sigm(pre[3][r]);
            float cn = fg * cr[r] + ig * gv;
            cr[r] = cn;
            hnew[r] = f2bf(og * tanh_f(cn));
        }

        if (g == 0) {
            ushort* hw = hbuf + (size_t)(t & 1) * (BB * HH);
#pragma unroll
            for (int r = 0; r < 4; ++r) {
                hw[(size_t)(bglob + r) * HH + jcol] = hnew[r];
                hsC[((size_t)(bglob + r) * Tc + tl) * HH + jcol] = hnew[r];
            }
        }

        if (tl + 1 < Tc) {
            __threadfence();   // release h writes
            grid.sync();
            __threadfence();   // acquire (invalidate stale lines)
        }
    }

    if (g == 0) {
#pragma unroll
        for (int r = 0; r < 4; ++r) cst[(size_t)(bglob + r) * HH + jcol] = cr[r];
    }
}

// ---------------------------------------------------------------- launch
extern "C" void kernel_launch(void* const* d_in, const int* in_sizes, int n_in,
                              void* d_out, int out_size, void* d_ws, size_t ws_size,
                              hipStream_t stream) {
    const float* seq  = (const float*)d_in[0];
    const float* Wih  = (const float*)d_in[1];
    const float* Whh  = (const float*)d_in[2];
    const float* bih  = (const float*)d_in[3];
    const float* bhh  = (const float*)d_in[4];
    const float* Wout = (const float*)d_in[5];
    const float* bout = (const float*)d_in[6];

    constexpr size_t MB = 1u << 20;
    char* ws = (char*)d_ws;
    ushort* wih_bf  = (ushort*)(ws);                       // 4 MB
    ushort* whh_bf  = (ushort*)(ws + 4 * MB);              // 8 MB
    ushort* wout_bf = (ushort*)(ws + 12 * MB);             // 1 MB
    float*  cst     = (float*) (ws + 13 * MB);             // 256 KB
    ushort* hbuf    = (ushort*)(ws + 13 * MB + 262144);    // 256 KB ping-pong
    char*   dynbase = ws + 14 * MB;

    int Tc = 512, lg = 9;
    while (Tc > 16) {
        size_t need = 14 * MB + (size_t)Tc * BB * (size_t)(G4 + HH) * 2;
        if (need <= ws_size) break;
        Tc >>= 1; --lg;
    }
    ushort* xpb = (ushort*)dynbase;
    ushort* hsC = (ushort*)(dynbase + (size_t)Tc * BB * G4 * 2);

    auto cvt = [&](const float* in, ushort* o, int n) {
        int n4 = n / 4;
        hipLaunchKernelGGL(cvt4, dim3((n4 + 255) / 256), dim3(256), 0, stream,
                           (const float4*)in, (ushort4*)o, n4);
    };
    cvt(Wih,  wih_bf,  G4 * II);
    cvt(Whh,  whh_bf,  G4 * HH);
    cvt(Wout, wout_bf, OO * HH);

    const int Mloc = BB * Tc;
    for (int t0 = 0; t0 < TT; t0 += Tc) {
        hipLaunchKernelGGL(gemm_xproj, dim3(G4 / 128, Mloc / 128), dim3(256), 0, stream,
                           seq, wih_bf, bih, bhh, xpb, lg, t0);

        const ushort* whh_c = whh_bf;
        const ushort* xp_c  = xpb;
        int t0v = t0, Tcv = Tc;
        void* args[] = { (void*)&whh_c, (void*)&xp_c, (void*)&hsC,
                         (void*)&hbuf, (void*)&cst, (void*)&Tcv, (void*)&t0v };
        hipLaunchCooperativeKernel((const void*)lstm_scan, dim3(256), dim3(256),
                                   args, 0, stream);

        hipLaunchKernelGGL(gemm_out, dim3(OO / 128, Mloc / 128), dim3(256), 0, stream,
                           hsC, wout_bf, bout, (float*)d_out, lg, t0);
    }
}

// Round 4
// 9011.732 us; speedup vs baseline: 4.5287x; 4.5287x over previous
//
#include <hip/hip_runtime.h>

#define DI __device__ __forceinline__

using f32x4  = __attribute__((ext_vector_type(4))) float;
using u16x8  = __attribute__((ext_vector_type(8))) unsigned short;
using bf16x8 = __attribute__((ext_vector_type(8))) __bf16;

constexpr int BB = 64;    // batch
constexpr int TT = 512;   // time
constexpr int II = 512;   // input dim
constexpr int HH = 1024;  // hidden
constexpr int G4 = 4096;  // 4*H
constexpr int OO = 512;   // output dim

DI unsigned short f2bf(float f) {
    unsigned int u = __builtin_bit_cast(unsigned int, f);
    u += 0x7fffu + ((u >> 16) & 1u);   // RNE
    return (unsigned short)(u >> 16);
}
DI float bf2f(unsigned short h) {
    unsigned int u = ((unsigned int)h) << 16;
    return __builtin_bit_cast(float, u);
}
DI f32x4 mfma_bf16(u16x8 a, u16x8 b, f32x4 c) {
    return __builtin_amdgcn_mfma_f32_16x16x32_bf16(
        __builtin_bit_cast(bf16x8, a), __builtin_bit_cast(bf16x8, b), c, 0, 0, 0);
}
DI float sigm(float x) { return 1.f / (1.f + __expf(-x)); }
DI float tanh_f(float x) { return 2.f / (1.f + __expf(-2.f * x)) - 1.f; }

// --- MALL-coherent (cache-bypassing) access helpers: no fences, no L2 flushes.
DI void h_store(ushort* p, unsigned short v) {
    __hip_atomic_store(p, v, __ATOMIC_RELAXED, __HIP_MEMORY_SCOPE_AGENT);
}
DI u16x8 h_load16(const ushort* p) {
    const unsigned* q = (const unsigned*)p;
    unsigned w0 = __hip_atomic_load(q + 0, __ATOMIC_RELAXED, __HIP_MEMORY_SCOPE_AGENT);
    unsigned w1 = __hip_atomic_load(q + 1, __ATOMIC_RELAXED, __HIP_MEMORY_SCOPE_AGENT);
    unsigned w2 = __hip_atomic_load(q + 2, __ATOMIC_RELAXED, __HIP_MEMORY_SCOPE_AGENT);
    unsigned w3 = __hip_atomic_load(q + 3, __ATOMIC_RELAXED, __HIP_MEMORY_SCOPE_AGENT);
    uint4 w = {w0, w1, w2, w3};
    return __builtin_bit_cast(u16x8, w);
}

// ---------------------------------------------------------------- cvt fp32->bf16
__global__ __launch_bounds__(256) void cvt4(const float4* __restrict__ in,
                                            ushort4* __restrict__ out, int n4) {
    int i = blockIdx.x * 256 + threadIdx.x;
    if (i < n4) {
        float4 v = in[i];
        ushort4 o;
        o.x = f2bf(v.x); o.y = f2bf(v.y); o.z = f2bf(v.z); o.w = f2bf(v.w);
        out[i] = o;
    }
}

// ---------------------------------------------------------------- xproj GEMM
__global__ __launch_bounds__(256)
void gemm_xproj(const float* __restrict__ seq, const ushort* __restrict__ Wih,
                const float* __restrict__ bih, const float* __restrict__ bhh,
                ushort* __restrict__ xp, int lgTc, int t0) {
    __shared__ ushort As[128 * 40];
    __shared__ ushort Bs[128 * 40];
    const int tid  = threadIdx.x;
    const int lane = tid & 63, wave = tid >> 6;
    const int wm = (wave >> 1) * 64, wn = (wave & 1) * 64;
    const int bn = blockIdx.x * 128;
    const int bm = blockIdx.y * 128;
    const int l15 = lane & 15, l4 = lane >> 4;

    const int srow = tid >> 1, shalf = tid & 1;
    const int rloc = bm + srow;
    const int bIdx = rloc >> lgTc, tl = rloc & ((1 << lgTc) - 1);
    const float*  gA = seq + ((size_t)bIdx * TT + t0 + tl) * II + shalf * 16;
    const ushort* gB = Wih + (size_t)(bn + srow) * II + shalf * 16;
    ushort* sA = &As[srow * 40 + shalf * 16];
    ushort* sB = &Bs[srow * 40 + shalf * 16];

    f32x4 acc[4][4] = {};
    alignas(16) float  raf[16];
    alignas(16) ushort rbf[16];

#define LOAD_A(kk)                                                        \
    { const float* p = gA + (kk) * 32;                                    \
      *(float4*)(raf + 0)  = *(const float4*)(p + 0);                     \
      *(float4*)(raf + 4)  = *(const float4*)(p + 4);                     \
      *(float4*)(raf + 8)  = *(const float4*)(p + 8);                     \
      *(float4*)(raf + 12) = *(const float4*)(p + 12); }
#define LOAD_B(kk)                                                        \
    { const ushort* p = gB + (kk) * 32;                                   \
      *(u16x8*)(rbf + 0) = *(const u16x8*)(p + 0);                        \
      *(u16x8*)(rbf + 8) = *(const u16x8*)(p + 8); }

    LOAD_A(0); LOAD_B(0);
    const int nk = II / 32;
    for (int kk = 0; kk < nk; ++kk) {
        __syncthreads();
        alignas(16) ushort cv[16];
#pragma unroll
        for (int j = 0; j < 16; ++j) cv[j] = f2bf(raf[j]);
        *(u16x8*)(sA + 0) = *(u16x8*)(cv + 0);
        *(u16x8*)(sA + 8) = *(u16x8*)(cv + 8);
        *(u16x8*)(sB + 0) = *(u16x8*)(rbf + 0);
        *(u16x8*)(sB + 8) = *(u16x8*)(rbf + 8);
        __syncthreads();
        if (kk + 1 < nk) { LOAD_A(kk + 1); LOAD_B(kk + 1); }
        u16x8 af[4], bfr[4];
#pragma unroll
        for (int i = 0; i < 4; ++i) {
            af[i]  = *(const u16x8*)&As[(wm + i * 16 + l15) * 40 + l4 * 8];
            bfr[i] = *(const u16x8*)&Bs[(wn + i * 16 + l15) * 40 + l4 * 8];
        }
#pragma unroll
        for (int mi = 0; mi < 4; ++mi)
#pragma unroll
            for (int ni = 0; ni < 4; ++ni)
                acc[mi][ni] = mfma_bf16(af[mi], bfr[ni], acc[mi][ni]);
    }
#undef LOAD_A
#undef LOAD_B

#pragma unroll
    for (int mi = 0; mi < 4; ++mi) {
#pragma unroll
        for (int ni = 0; ni < 4; ++ni) {
            const int row = bm + wm + mi * 16 + l4 * 4;
            const int col = bn + wn + ni * 16 + l15;
            const float bsum = bih[col] + bhh[col];
#pragma unroll
            for (int r = 0; r < 4; ++r)
                xp[(size_t)(row + r) * G4 + col] = f2bf(acc[mi][ni][r] + bsum);
        }
    }
}

// ---------------------------------------------------------------- output GEMM
__global__ __launch_bounds__(256)
void gemm_out(const ushort* __restrict__ hsC, const ushort* __restrict__ Wout,
              const float* __restrict__ bout, float* __restrict__ out,
              int lgTc, int t0) {
    __shared__ ushort As[128 * 40];
    __shared__ ushort Bs[128 * 40];
    const int tid  = threadIdx.x;
    const int lane = tid & 63, wave = tid >> 6;
    const int wm = (wave >> 1) * 64, wn = (wave & 1) * 64;
    const int bn = blockIdx.x * 128;
    const int bm = blockIdx.y * 128;
    const int l15 = lane & 15, l4 = lane >> 4;

    const int srow = tid >> 1, shalf = tid & 1;
    const ushort* gA = hsC  + (size_t)(bm + srow) * HH + shalf * 16;
    const ushort* gB = Wout + (size_t)(bn + srow) * HH + shalf * 16;
    ushort* sA = &As[srow * 40 + shalf * 16];
    ushort* sB = &Bs[srow * 40 + shalf * 16];

    f32x4 acc[4][4] = {};
    u16x8 ra0 = *(const u16x8*)(gA + 0), ra1 = *(const u16x8*)(gA + 8);
    u16x8 rb0 = *(const u16x8*)(gB + 0), rb1 = *(const u16x8*)(gB + 8);

    const int nk = HH / 32;
    for (int kk = 0; kk < nk; ++kk) {
        __syncthreads();
        *(u16x8*)(sA + 0) = ra0; *(u16x8*)(sA + 8) = ra1;
        *(u16x8*)(sB + 0) = rb0; *(u16x8*)(sB + 8) = rb1;
        __syncthreads();
        if (kk + 1 < nk) {
            const ushort* pa = gA + (kk + 1) * 32;
            const ushort* pb = gB + (kk + 1) * 32;
            ra0 = *(const u16x8*)(pa + 0); ra1 = *(const u16x8*)(pa + 8);
            rb0 = *(const u16x8*)(pb + 0); rb1 = *(const u16x8*)(pb + 8);
        }
        u16x8 af[4], bfr[4];
#pragma unroll
        for (int i = 0; i < 4; ++i) {
            af[i]  = *(const u16x8*)&As[(wm + i * 16 + l15) * 40 + l4 * 8];
            bfr[i] = *(const u16x8*)&Bs[(wn + i * 16 + l15) * 40 + l4 * 8];
        }
#pragma unroll
        for (int mi = 0; mi < 4; ++mi)
#pragma unroll
            for (int ni = 0; ni < 4; ++ni)
                acc[mi][ni] = mfma_bf16(af[mi], bfr[ni], acc[mi][ni]);
    }

    const int Tcm1 = (1 << lgTc) - 1;
#pragma unroll
    for (int mi = 0; mi < 4; ++mi) {
#pragma unroll
        for (int ni = 0; ni < 4; ++ni) {
            const int row = bm + wm + mi * 16 + l4 * 4;
            const int col = bn + wn + ni * 16 + l15;
            const float bs = bout[col];
#pragma unroll
            for (int r = 0; r < 4; ++r) {
                const int rl = row + r;
                const int bIdx = rl >> lgTc, tl = rl & Tcm1;
                out[((size_t)bIdx * TT + t0 + tl) * OO + col] = acc[mi][ni][r] + bs;
            }
        }
    }
}

// ---------------------------------------------------------------- persistent scan
// 256 blocks = 4 batch-groups (16 batches) x 64 j-slices (16 cols x 4 gates).
// h exchange goes through MALL (sc0/sc1 atomics) -> NO fences, NO L2 flushes.
// Per-batch-group 64-block barrier on a monotonic MALL counter.
__global__ __launch_bounds__(256, 1)
void lstm_scan(const ushort* __restrict__ Whh,  // [4096,1024] bf16
               const ushort* __restrict__ xp,   // [B*Tc,4096] bf16 (biases folded)
               ushort* __restrict__ hsC,        // [B*Tc,1024] bf16
               ushort* __restrict__ hbuf,       // [2][64*1024] bf16 ping-pong (MALL)
               float* __restrict__ cst,         // [64*1024] fp32
               unsigned* __restrict__ bar,      // [4] counters, 128B apart
               int Tc, int t0) {
    __shared__ ushort Ws[64 * 1024];   // 128 KB, fragment layout
    const int tid  = threadIdx.x;
    const int lane = tid & 63, wave = tid >> 6;
    const int l15 = lane & 15, l4 = lane >> 4;
    const int g = l15 >> 2, jj = l15 & 3;
    const int bx = blockIdx.x;
    const int bg = bx >> 6, js = bx & 63;
    const int j0 = js * 16;

    // ---- stage Whh slice -> LDS fragment layout (once per launch)
    {
        const int r64 = tid >> 2, q = tid & 3;
        const int wv = r64 >> 4, c = r64 & 15;
        const int gg = c >> 2, j2 = c & 3;
        const size_t grow = (size_t)(gg * HH + j0 + wv * 4 + j2) * HH;
#pragma unroll 4
        for (int seg = 0; seg < 32; ++seg) {
            u16x8 v = *(const u16x8*)(Whh + grow + seg * 32 + q * 8);
            *(u16x8*)&Ws[(((wv * 32 + seg) * 4 + q) * 16 + c) * 8] = v;
        }
    }
    __syncthreads();

    const int bglob = bg * 16 + l4 * 4;        // + r
    const int jcol  = j0 + wave * 4 + jj;      // this lane's hidden column
    const ushort* wsbase = &Ws[(wave * 32 * 64 + lane) * 8];
    unsigned* myctr = bar + bg * 32;           // 128B-spaced counters

    float cr[4];
    if (t0 > 0) {
#pragma unroll
        for (int r = 0; r < 4; ++r) cr[r] = cst[(size_t)(bglob + r) * HH + jcol];
    } else {
#pragma unroll
        for (int r = 0; r < 4; ++r) cr[r] = 0.f;
    }

    for (int tl = 0; tl < Tc; ++tl) {
        const int t = t0 + tl;

        float xg[4];
#pragma unroll
        for (int r = 0; r < 4; ++r)
            xg[r] = bf2f(xp[((size_t)(bglob + r) * Tc + tl) * G4 + g * HH + jcol]);

        f32x4 ac0 = {}, ac1 = {};
        if (t > 0) {
            const ushort* hprev = hbuf + (size_t)((t - 1) & 1) * (BB * HH);
            const ushort* gA = hprev + (size_t)(bg * 16 + l15) * HH + l4 * 8;
            u16x8 apf[4];
#pragma unroll
            for (int p = 0; p < 4; ++p) apf[p] = h_load16(gA + p * 32);
#pragma unroll
            for (int kk = 0; kk < 32; ++kk) {
                u16x8 a = apf[kk & 3];
                if (kk + 4 < 32) apf[kk & 3] = h_load16(gA + (kk + 4) * 32);
                u16x8 b = *(const u16x8*)(wsbase + (size_t)kk * 64 * 8);
                if (kk & 1) ac1 = mfma_bf16(a, b, ac1);
                else        ac0 = mfma_bf16(a, b, ac0);
            }
        }

        f32x4 s;
#pragma unroll
        for (int r = 0; r < 4; ++r) s[r] = ac0[r] + ac1[r] + xg[r];

        float pre[4][4];
#pragma unroll
        for (int gp = 0; gp < 4; ++gp) {
            const int src = (l4 << 4) + gp * 4 + jj;
#pragma unroll
            for (int r = 0; r < 4; ++r) pre[gp][r] = __shfl(s[r], src, 64);
        }

        unsigned short hnew[4];
#pragma unroll
        for (int r = 0; r < 4; ++r) {
            float ig = sigm(pre[0][r]);
            float fg = sigm(pre[1][r]);
            float gv = tanh_f(pre[2][r]);
            float og = sigm(pre[3][r]);
            float cn = fg * cr[r] + ig * gv;
            cr[r] = cn;
            hnew[r] = f2bf(og * tanh_f(cn));
        }

        if (g == 0) {
            ushort* hw = hbuf + (size_t)(t & 1) * (BB * HH);
#pragma unroll
            for (int r = 0; r < 4; ++r) {
                h_store(&hw[(size_t)(bglob + r) * HH + jcol], hnew[r]);
                hsC[((size_t)(bglob + r) * Tc + tl) * HH + jcol] = hnew[r];
            }
        }

        if (tl + 1 < Tc) {
            // own h stores reached MALL:
            asm volatile("s_waitcnt vmcnt(0)" ::: "memory");
            __syncthreads();
            if (tid == 0) {
                __hip_atomic_fetch_add(myctr, 1u, __ATOMIC_RELAXED,
                                       __HIP_MEMORY_SCOPE_AGENT);
                const unsigned tgt = (unsigned)(tl + 1) * 64u;
                while (__hip_atomic_load(myctr, __ATOMIC_RELAXED,
                                         __HIP_MEMORY_SCOPE_AGENT) < tgt)
                    __builtin_amdgcn_s_sleep(2);
            }
            __syncthreads();
            __builtin_amdgcn_sched_barrier(0);
        }
    }

    if (g == 0) {
#pragma unroll
        for (int r = 0; r < 4; ++r) cst[(size_t)(bglob + r) * HH + jcol] = cr[r];
    }
}

// ---------------------------------------------------------------- launch
extern "C" void kernel_launch(void* const* d_in, const int* in_sizes, int n_in,
                              void* d_out, int out_size, void* d_ws, size_t ws_size,
                              hipStream_t stream) {
    const float* seq  = (const float*)d_in[0];
    const float* Wih  = (const float*)d_in[1];
    const float* Whh  = (const float*)d_in[2];
    const float* bih  = (const float*)d_in[3];
    const float* bhh  = (const float*)d_in[4];
    const float* Wout = (const float*)d_in[5];
    const float* bout = (const float*)d_in[6];

    constexpr size_t MB = 1u << 20;
    char* ws = (char*)d_ws;
    ushort*   wih_bf  = (ushort*)(ws);                       // 4 MB
    ushort*   whh_bf  = (ushort*)(ws + 4 * MB);              // 8 MB
    ushort*   wout_bf = (ushort*)(ws + 12 * MB);             // 1 MB
    float*    cst     = (float*) (ws + 13 * MB);             // 256 KB
    ushort*   hbuf    = (ushort*)(ws + 13 * MB + 262144);    // 256 KB ping-pong
    unsigned* bar     = (unsigned*)(ws + 13 * MB + 524288);  // 512 B counters
    char*     dynbase = ws + 14 * MB;

    int Tc = 512, lg = 9;
    while (Tc > 16) {
        size_t need = 14 * MB + (size_t)Tc * BB * (size_t)(G4 + HH) * 2;
        if (need <= ws_size) break;
        Tc >>= 1; --lg;
    }
    ushort* xpb = (ushort*)dynbase;
    ushort* hsC = (ushort*)(dynbase + (size_t)Tc * BB * G4 * 2);

    auto cvt = [&](const float* in, ushort* o, int n) {
        int n4 = n / 4;
        hipLaunchKernelGGL(cvt4, dim3((n4 + 255) / 256), dim3(256), 0, stream,
                           (const float4*)in, (ushort4*)o, n4);
    };
    cvt(Wih,  wih_bf,  G4 * II);
    cvt(Whh,  whh_bf,  G4 * HH);
    cvt(Wout, wout_bf, OO * HH);

    const int Mloc = BB * Tc;
    for (int t0 = 0; t0 < TT; t0 += Tc) {
        hipLaunchKernelGGL(gemm_xproj, dim3(G4 / 128, Mloc / 128), dim3(256), 0, stream,
                           seq, wih_bf, bih, bhh, xpb, lg, t0);

        hipMemsetAsync(bar, 0, 512, stream);   // fresh barrier counters

        const ushort* whh_c = whh_bf;
        const ushort* xp_c  = xpb;
        int t0v = t0, Tcv = Tc;
        void* args[] = { (void*)&whh_c, (void*)&xp_c, (void*)&hsC, (void*)&hbuf,
                         (void*)&cst, (void*)&bar, (void*)&Tcv, (void*)&t0v };
        hipLaunchCooperativeKernel((const void*)lstm_scan, dim3(256), dim3(256),
                                   args, 0, stream);

        hipLaunchKernelGGL(gemm_out, dim3(OO / 128, Mloc / 128), dim3(256), 0, stream,
                           hsC, wout_bf, bout, (float*)d_out, lg, t0);
    }
}

// Round 6
// 3396.658 us; speedup vs baseline: 12.0152x; 2.6531x over previous
//
#include <hip/hip_runtime.h>

#define DI __device__ __forceinline__

using f32x4  = __attribute__((ext_vector_type(4))) float;
using u16x8  = __attribute__((ext_vector_type(8))) unsigned short;
using u32x4  = __attribute__((ext_vector_type(4))) unsigned int;
using bf16x8 = __attribute__((ext_vector_type(8))) __bf16;

constexpr int BB = 64;    // batch
constexpr int TT = 512;   // time
constexpr int II = 512;   // input dim
constexpr int HH = 1024;  // hidden
constexpr int G4 = 4096;  // 4*H
constexpr int OO = 512;   // output dim

DI unsigned short f2bf(float f) {
    unsigned int u = __builtin_bit_cast(unsigned int, f);
    u += 0x7fffu + ((u >> 16) & 1u);   // RNE
    return (unsigned short)(u >> 16);
}
DI float bf2f(unsigned short h) {
    unsigned int u = ((unsigned int)h) << 16;
    return __builtin_bit_cast(float, u);
}
DI f32x4 mfma_bf16(u16x8 a, u16x8 b, f32x4 c) {
    return __builtin_amdgcn_mfma_f32_16x16x32_bf16(
        __builtin_bit_cast(bf16x8, a), __builtin_bit_cast(bf16x8, b), c, 0, 0, 0);
}
DI float sigm(float x) { return 1.f / (1.f + __expf(-x)); }
DI float tanh_f(float x) { return 2.f / (1.f + __expf(-2.f * x)) - 1.f; }

// ---------------------------------------------------------------- cvt fp32->bf16
__global__ __launch_bounds__(256) void cvt4(const float4* __restrict__ in,
                                            ushort4* __restrict__ out, int n4) {
    int i = blockIdx.x * 256 + threadIdx.x;
    if (i < n4) {
        float4 v = in[i];
        ushort4 o;
        o.x = f2bf(v.x); o.y = f2bf(v.y); o.z = f2bf(v.z); o.w = f2bf(v.w);
        out[i] = o;
    }
}

// ---------------------------------------------------------------- xproj GEMM
__global__ __launch_bounds__(256)
void gemm_xproj(const float* __restrict__ seq, const ushort* __restrict__ Wih,
                const float* __restrict__ bih, const float* __restrict__ bhh,
                ushort* __restrict__ xp, int lgTc, int t0) {
    __shared__ ushort As[128 * 40];
    __shared__ ushort Bs[128 * 40];
    const int tid  = threadIdx.x;
    const int lane = tid & 63, wave = tid >> 6;
    const int wm = (wave >> 1) * 64, wn = (wave & 1) * 64;
    const int bn = blockIdx.x * 128;
    const int bm = blockIdx.y * 128;
    const int l15 = lane & 15, l4 = lane >> 4;

    const int srow = tid >> 1, shalf = tid & 1;
    const int rloc = bm + srow;
    const int bIdx = rloc >> lgTc, tl = rloc & ((1 << lgTc) - 1);
    const float*  gA = seq + ((size_t)bIdx * TT + t0 + tl) * II + shalf * 16;
    const ushort* gB = Wih + (size_t)(bn + srow) * II + shalf * 16;
    ushort* sA = &As[srow * 40 + shalf * 16];
    ushort* sB = &Bs[srow * 40 + shalf * 16];

    f32x4 acc[4][4] = {};
    alignas(16) float  raf[16];
    alignas(16) ushort rbf[16];

#define LOAD_A(kk)                                                        \
    { const float* p = gA + (kk) * 32;                                    \
      *(float4*)(raf + 0)  = *(const float4*)(p + 0);                     \
      *(float4*)(raf + 4)  = *(const float4*)(p + 4);                     \
      *(float4*)(raf + 8)  = *(const float4*)(p + 8);                     \
      *(float4*)(raf + 12) = *(const float4*)(p + 12); }
#define LOAD_B(kk)                                                        \
    { const ushort* p = gB + (kk) * 32;                                   \
      *(u16x8*)(rbf + 0) = *(const u16x8*)(p + 0);                        \
      *(u16x8*)(rbf + 8) = *(const u16x8*)(p + 8); }

    LOAD_A(0); LOAD_B(0);
    const int nk = II / 32;
    for (int kk = 0; kk < nk; ++kk) {
        __syncthreads();
        alignas(16) ushort cv[16];
#pragma unroll
        for (int j = 0; j < 16; ++j) cv[j] = f2bf(raf[j]);
        *(u16x8*)(sA + 0) = *(u16x8*)(cv + 0);
        *(u16x8*)(sA + 8) = *(u16x8*)(cv + 8);
        *(u16x8*)(sB + 0) = *(u16x8*)(rbf + 0);
        *(u16x8*)(sB + 8) = *(u16x8*)(rbf + 8);
        __syncthreads();
        if (kk + 1 < nk) { LOAD_A(kk + 1); LOAD_B(kk + 1); }
        u16x8 af[4], bfr[4];
#pragma unroll
        for (int i = 0; i < 4; ++i) {
            af[i]  = *(const u16x8*)&As[(wm + i * 16 + l15) * 40 + l4 * 8];
            bfr[i] = *(const u16x8*)&Bs[(wn + i * 16 + l15) * 40 + l4 * 8];
        }
#pragma unroll
        for (int mi = 0; mi < 4; ++mi)
#pragma unroll
            for (int ni = 0; ni < 4; ++ni)
                acc[mi][ni] = mfma_bf16(af[mi], bfr[ni], acc[mi][ni]);
    }
#undef LOAD_A
#undef LOAD_B

#pragma unroll
    for (int mi = 0; mi < 4; ++mi) {
#pragma unroll
        for (int ni = 0; ni < 4; ++ni) {
            const int row = bm + wm + mi * 16 + l4 * 4;
            const int col = bn + wn + ni * 16 + l15;
            const float bsum = bih[col] + bhh[col];
#pragma unroll
            for (int r = 0; r < 4; ++r)
                xp[(size_t)(row + r) * G4 + col] = f2bf(acc[mi][ni][r] + bsum);
        }
    }
}

// ---------------------------------------------------------------- output GEMM
__global__ __launch_bounds__(256)
void gemm_out(const ushort* __restrict__ hsC, const ushort* __restrict__ Wout,
              const float* __restrict__ bout, float* __restrict__ out,
              int lgTc, int t0) {
    __shared__ ushort As[128 * 40];
    __shared__ ushort Bs[128 * 40];
    const int tid  = threadIdx.x;
    const int lane = tid & 63, wave = tid >> 6;
    const int wm = (wave >> 1) * 64, wn = (wave & 1) * 64;
    const int bn = blockIdx.x * 128;
    const int bm = blockIdx.y * 128;
    const int l15 = lane & 15, l4 = lane >> 4;

    const int srow = tid >> 1, shalf = tid & 1;
    const ushort* gA = hsC  + (size_t)(bm + srow) * HH + shalf * 16;
    const ushort* gB = Wout + (size_t)(bn + srow) * HH + shalf * 16;
    ushort* sA = &As[srow * 40 + shalf * 16];
    ushort* sB = &Bs[srow * 40 + shalf * 16];

    f32x4 acc[4][4] = {};
    u16x8 ra0 = *(const u16x8*)(gA + 0), ra1 = *(const u16x8*)(gA + 8);
    u16x8 rb0 = *(const u16x8*)(gB + 0), rb1 = *(const u16x8*)(gB + 8);

    const int nk = HH / 32;
    for (int kk = 0; kk < nk; ++kk) {
        __syncthreads();
        *(u16x8*)(sA + 0) = ra0; *(u16x8*)(sA + 8) = ra1;
        *(u16x8*)(sB + 0) = rb0; *(u16x8*)(sB + 8) = rb1;
        __syncthreads();
        if (kk + 1 < nk) {
            const ushort* pa = gA + (kk + 1) * 32;
            const ushort* pb = gB + (kk + 1) * 32;
            ra0 = *(const u16x8*)(pa + 0); ra1 = *(const u16x8*)(pa + 8);
            rb0 = *(const u16x8*)(pb + 0); rb1 = *(const u16x8*)(pb + 8);
        }
        u16x8 af[4], bfr[4];
#pragma unroll
        for (int i = 0; i < 4; ++i) {
            af[i]  = *(const u16x8*)&As[(wm + i * 16 + l15) * 40 + l4 * 8];
            bfr[i] = *(const u16x8*)&Bs[(wn + i * 16 + l15) * 40 + l4 * 8];
        }
#pragma unroll
        for (int mi = 0; mi < 4; ++mi)
#pragma unroll
            for (int ni = 0; ni < 4; ++ni)
                acc[mi][ni] = mfma_bf16(af[mi], bfr[ni], acc[mi][ni]);
    }

    const int Tcm1 = (1 << lgTc) - 1;
#pragma unroll
    for (int mi = 0; mi < 4; ++mi) {
#pragma unroll
        for (int ni = 0; ni < 4; ++ni) {
            const int row = bm + wm + mi * 16 + l4 * 4;
            const int col = bn + wn + ni * 16 + l15;
            const float bs = bout[col];
#pragma unroll
            for (int r = 0; r < 4; ++r) {
                const int rl = row + r;
                const int bIdx = rl >> lgTc, tl = rl & Tcm1;
                out[((size_t)bIdx * TT + t0 + tl) * OO + col] = acc[mi][ni][r] + bs;
            }
        }
    }
}

// ---------------------------------------------------------------- persistent scan
// 256 blocks = 4 batch-groups (16 batches) x 64 j-slices (16 cols x 4 gates).
// Whh fragments in registers (loaded once). h exchange via sc0/sc1 dwordx4
// through MALL; per-group barrier = 64 per-block flag words, no atomics.
__global__ __launch_bounds__(256, 1)
void lstm_scan(const ushort* __restrict__ Whh,  // [4096,1024] bf16
               const ushort* __restrict__ xp,   // [B*Tc,4096] bf16 (biases folded)
               ushort* __restrict__ hsC,        // [B*Tc,1024] bf16
               ushort* __restrict__ hbuf,       // [2][64*1024] bf16 ping-pong (MALL)
               float* __restrict__ cst,         // [64*1024] fp32
               unsigned* __restrict__ bar,      // [4][64] flags (dwords)
               int Tc, int t0) {
    __shared__ ushort HsB[16 * 1024];            // 32 KB staged h slab (swizzled)
    alignas(16) __shared__ ushort hpack[16][16]; // 512 B packed h output
    const int tid  = threadIdx.x;
    const int lane = tid & 63, wave = tid >> 6;
    const int l15 = lane & 15, l4 = lane >> 4;
    const int g = l15 >> 2, jj = l15 & 3;
    const int bg = blockIdx.x >> 6, js = blockIdx.x & 63;
    const int j0 = js * 16;

    // ---- Whh fragments -> registers (one time, plain cached loads)
    u16x8 bfr[32];
    {
        const ushort* gB = Whh +
            (size_t)(g * HH + j0 + wave * 4 + jj) * HH + l4 * 8;
#pragma unroll
        for (int kk = 0; kk < 32; ++kk)
            bfr[kk] = *(const u16x8*)(gB + kk * 32);
    }

    const int bglob = bg * 16 + l4 * 4;        // + r
    const int jcol  = j0 + wave * 4 + jj;      // this lane's hidden column
    const int srow  = tid >> 4, ss = tid & 15; // staging map: 16 rows x 16 threads

    float cr[4];
    if (t0 > 0) {
#pragma unroll
        for (int r = 0; r < 4; ++r) cr[r] = cst[(size_t)(bglob + r) * HH + jcol];
    } else {
#pragma unroll
        for (int r = 0; r < 4; ++r) cr[r] = 0.f;
    }

    for (int tl = 0; tl < Tc; ++tl) {
        const int t = t0 + tl;

        // xp preacts (plain cached loads, issued before the asm chain)
        float xg[4];
#pragma unroll
        for (int r = 0; r < 4; ++r)
            xg[r] = bf2f(xp[((size_t)(bglob + r) * Tc + tl) * G4 + g * HH + jcol]);

        f32x4 ac0 = {}, ac1 = {};
        if (t > 0) {
            // ---- cooperative slab load: 32 KB via 8x dwordx4 sc1 per thread
            const char* hb = (const char*)hbuf +
                ((size_t)((t - 1) & 1) * (BB * HH) + (size_t)(bg * 16 + srow) * HH) * 2
                + ss * 16;
            u32x4 hv[8];
            asm volatile("global_load_dwordx4 %0, %1, off sc0 sc1"
                         : "=&v"(hv[0]) : "v"(hb) : "memory");
            asm volatile("global_load_dwordx4 %0, %1, off offset:256 sc0 sc1"
                         : "=&v"(hv[1]) : "v"(hb));
            asm volatile("global_load_dwordx4 %0, %1, off offset:512 sc0 sc1"
                         : "=&v"(hv[2]) : "v"(hb));
            asm volatile("global_load_dwordx4 %0, %1, off offset:768 sc0 sc1"
                         : "=&v"(hv[3]) : "v"(hb));
            asm volatile("global_load_dwordx4 %0, %1, off offset:1024 sc0 sc1"
                         : "=&v"(hv[4]) : "v"(hb));
            asm volatile("global_load_dwordx4 %0, %1, off offset:1280 sc0 sc1"
                         : "=&v"(hv[5]) : "v"(hb));
            asm volatile("global_load_dwordx4 %0, %1, off offset:1536 sc0 sc1"
                         : "=&v"(hv[6]) : "v"(hb));
            asm volatile("global_load_dwordx4 %0, %1, off offset:1792 sc0 sc1"
                         : "=&v"(hv[7]) : "v"(hb));
            asm volatile("s_waitcnt vmcnt(0)" ::: "memory");
            __builtin_amdgcn_sched_barrier(0);
            // LDS stage with XOR swizzle (chunk ^= row&7): <=2-way conflicts
#pragma unroll
            for (int k = 0; k < 8; ++k)
                *(u16x8*)&HsB[srow * 1024 + (((ss + 16 * k) ^ (srow & 7)) * 8)] =
                    __builtin_bit_cast(u16x8, hv[k]);
            __syncthreads();
            // ---- MFMA over K=1024, B-fragments already in registers
#pragma unroll
            for (int kk = 0; kk < 32; ++kk) {
                u16x8 a = *(const u16x8*)
                    &HsB[l15 * 1024 + (((l4 + 4 * kk) ^ (l15 & 7)) * 8)];
                if (kk & 1) ac1 = mfma_bf16(a, bfr[kk], ac1);
                else        ac0 = mfma_bf16(a, bfr[kk], ac0);
            }
        }

        // per-lane preact (own gate), gather all 4 gates via shuffles
        f32x4 s;
#pragma unroll
        for (int r = 0; r < 4; ++r) s[r] = ac0[r] + ac1[r] + xg[r];

        float pre[4][4];
#pragma unroll
        for (int gp = 0; gp < 4; ++gp) {
            const int src = (l4 << 4) + gp * 4 + jj;
#pragma unroll
            for (int r = 0; r < 4; ++r) pre[gp][r] = __shfl(s[r], src, 64);
        }

        unsigned short hnew[4];
#pragma unroll
        for (int r = 0; r < 4; ++r) {
            float ig = sigm(pre[0][r]);
            float fg = sigm(pre[1][r]);
            float gv = tanh_f(pre[2][r]);
            float og = sigm(pre[3][r]);
            float cn = fg * cr[r] + ig * gv;
            cr[r] = cn;
            hnew[r] = f2bf(og * tanh_f(cn));
        }

        if (g == 0) {
#pragma unroll
            for (int r = 0; r < 4; ++r) hpack[l4 * 4 + r][wave * 4 + jj] = hnew[r];
        }
        __syncthreads();

        if (tid < 16) {
            u32x4 lo = *(const u32x4*)&hpack[tid][0];
            u32x4 hi = *(const u32x4*)&hpack[tid][8];
            char* hw = (char*)hbuf +
                ((size_t)(t & 1) * (BB * HH) + (size_t)(bg * 16 + tid) * HH + j0) * 2;
            asm volatile("global_store_dwordx4 %0, %1, off sc0 sc1"
                         :: "v"(hw), "v"(lo) : "memory");
            asm volatile("global_store_dwordx4 %0, %1, off offset:16 sc0 sc1"
                         :: "v"(hw), "v"(hi) : "memory");
            u32x4* hc = (u32x4*)&hsC[((size_t)(bg * 16 + tid) * Tc + tl) * HH + j0];
            hc[0] = lo; hc[1] = hi;
        }

        if (tl + 1 < Tc) {
            asm volatile("s_waitcnt vmcnt(0)" ::: "memory");
            __syncthreads();                     // all h stores drained
            if (tid == 0) {
                unsigned* fl = bar + bg * 64 + js;
                unsigned v = (unsigned)(tl + 1);
                asm volatile("global_store_dword %0, %1, off sc0 sc1"
                             :: "v"(fl), "v"(v) : "memory");
            }
            if (wave == 0) {                     // 16 lanes poll 64 flags
                const u32x4* fb = (const u32x4*)(bar + bg * 64) + l15;
                for (;;) {
                    u32x4 f;
                    asm volatile("global_load_dwordx4 %0, %1, off sc0 sc1\n\t"
                                 "s_waitcnt vmcnt(0)"
                                 : "=&v"(f) : "v"(fb) : "memory");
                    unsigned m = f[0] < f[1] ? f[0] : f[1];
                    m = m < f[2] ? m : f[2];
                    m = m < f[3] ? m : f[3];
                    bool rdy = (lane < 16) ? (m > (unsigned)tl) : true;
                    if (__all(rdy)) break;
                    __builtin_amdgcn_s_sleep(1);
                }
            }
            __syncthreads();
        }
    }

    if (g == 0) {
#pragma unroll
        for (int r = 0; r < 4; ++r) cst[(size_t)(bglob + r) * HH + jcol] = cr[r];
    }
}

// ---------------------------------------------------------------- launch
extern "C" void kernel_launch(void* const* d_in, const int* in_sizes, int n_in,
                              void* d_out, int out_size, void* d_ws, size_t ws_size,
                              hipStream_t stream) {
    const float* seq  = (const float*)d_in[0];
    const float* Wih  = (const float*)d_in[1];
    const float* Whh  = (const float*)d_in[2];
    const float* bih  = (const float*)d_in[3];
    const float* bhh  = (const float*)d_in[4];
    const float* Wout = (const float*)d_in[5];
    const float* bout = (const float*)d_in[6];

    constexpr size_t MB = 1u << 20;
    char* ws = (char*)d_ws;
    ushort*   wih_bf  = (ushort*)(ws);                       // 4 MB
    ushort*   whh_bf  = (ushort*)(ws + 4 * MB);              // 8 MB
    ushort*   wout_bf = (ushort*)(ws + 12 * MB);             // 1 MB
    float*    cst     = (float*) (ws + 13 * MB);             // 256 KB
    ushort*   hbuf    = (ushort*)(ws + 13 * MB + 262144);    // 256 KB ping-pong
    unsigned* bar     = (unsigned*)(ws + 13 * MB + 524288);  // 1 KB flags
    char*     dynbase = ws + 14 * MB;

    int Tc = 512, lg = 9;
    while (Tc > 16) {
        size_t need = 14 * MB + (size_t)Tc * BB * (size_t)(G4 + HH) * 2;
        if (need <= ws_size) break;
        Tc >>= 1; --lg;
    }
    ushort* xpb = (ushort*)dynbase;
    ushort* hsC = (ushort*)(dynbase + (size_t)Tc * BB * G4 * 2);

    auto cvt = [&](const float* in, ushort* o, int n) {
        int n4 = n / 4;
        hipLaunchKernelGGL(cvt4, dim3((n4 + 255) / 256), dim3(256), 0, stream,
                           (const float4*)in, (ushort4*)o, n4);
    };
    cvt(Wih,  wih_bf,  G4 * II);
    cvt(Whh,  whh_bf,  G4 * HH);
    cvt(Wout, wout_bf, OO * HH);

    const int Mloc = BB * Tc;
    for (int t0 = 0; t0 < TT; t0 += Tc) {
        hipLaunchKernelGGL(gemm_xproj, dim3(G4 / 128, Mloc / 128), dim3(256), 0, stream,
                           seq, wih_bf, bih, bhh, xpb, lg, t0);

        (void)hipMemsetAsync(bar, 0, 1024, stream);   // fresh barrier flags

        const ushort* whh_c = whh_bf;
        const ushort* xp_c  = xpb;
        int t0v = t0, Tcv = Tc;
        void* args[] = { (void*)&whh_c, (void*)&xp_c, (void*)&hsC, (void*)&hbuf,
                         (void*)&cst, (void*)&bar, (void*)&Tcv, (void*)&t0v };
        (void)hipLaunchCooperativeKernel((const void*)lstm_scan, dim3(256), dim3(256),
                                         args, 0, stream);

        hipLaunchKernelGGL(gemm_out, dim3(OO / 128, Mloc / 128), dim3(256), 0, stream,
                           hsC, wout_bf, bout, (float*)d_out, lg, t0);
    }
}

// Round 8
// 3267.597 us; speedup vs baseline: 12.4897x; 1.0395x over previous
//
#include <hip/hip_runtime.h>

#define DI __device__ __forceinline__

using f32x4  = __attribute__((ext_vector_type(4))) float;
using u16x8  = __attribute__((ext_vector_type(8))) unsigned short;
using u32x4  = __attribute__((ext_vector_type(4))) unsigned int;
using bf16x8 = __attribute__((ext_vector_type(8))) __bf16;

constexpr int BB = 64;    // batch
constexpr int TT = 512;   // time
constexpr int II = 512;   // input dim
constexpr int HH = 1024;  // hidden
constexpr int G4 = 4096;  // 4*H
constexpr int OO = 512;   // output dim

DI unsigned short f2bf(float f) {
    unsigned int u = __builtin_bit_cast(unsigned int, f);
    u += 0x7fffu + ((u >> 16) & 1u);   // RNE
    return (unsigned short)(u >> 16);
}
DI float bf2f(unsigned short h) {
    unsigned int u = ((unsigned int)h) << 16;
    return __builtin_bit_cast(float, u);
}
DI f32x4 mfma_bf16(u16x8 a, u16x8 b, f32x4 c) {
    return __builtin_amdgcn_mfma_f32_16x16x32_bf16(
        __builtin_bit_cast(bf16x8, a), __builtin_bit_cast(bf16x8, b), c, 0, 0, 0);
}
DI float sigm(float x) { return 1.f / (1.f + __expf(-x)); }
DI float tanh_f(float x) { return 2.f / (1.f + __expf(-2.f * x)) - 1.f; }

// ---------------------------------------------------------------- cvt fp32->bf16
__global__ __launch_bounds__(256) void cvt4(const float4* __restrict__ in,
                                            ushort4* __restrict__ out, int n4) {
    int i = blockIdx.x * 256 + threadIdx.x;
    if (i < n4) {
        float4 v = in[i];
        ushort4 o;
        o.x = f2bf(v.x); o.y = f2bf(v.y); o.z = f2bf(v.z); o.w = f2bf(v.w);
        out[i] = o;
    }
}

// ---------------------------------------------------------------- xproj GEMM
__global__ __launch_bounds__(256)
void gemm_xproj(const float* __restrict__ seq, const ushort* __restrict__ Wih,
                const float* __restrict__ bih, const float* __restrict__ bhh,
                ushort* __restrict__ xp, int lgTc, int t0) {
    __shared__ ushort As[128 * 40];
    __shared__ ushort Bs[128 * 40];
    const int tid  = threadIdx.x;
    const int lane = tid & 63, wave = tid >> 6;
    const int wm = (wave >> 1) * 64, wn = (wave & 1) * 64;
    const int bn = blockIdx.x * 128;
    const int bm = blockIdx.y * 128;
    const int l15 = lane & 15, l4 = lane >> 4;

    const int srow = tid >> 1, shalf = tid & 1;
    const int rloc = bm + srow;
    const int bIdx = rloc >> lgTc, tl = rloc & ((1 << lgTc) - 1);
    const float*  gA = seq + ((size_t)bIdx * TT + t0 + tl) * II + shalf * 16;
    const ushort* gB = Wih + (size_t)(bn + srow) * II + shalf * 16;
    ushort* sA = &As[srow * 40 + shalf * 16];
    ushort* sB = &Bs[srow * 40 + shalf * 16];

    f32x4 acc[4][4] = {};
    alignas(16) float  raf[16];
    alignas(16) ushort rbf[16];

#define LOAD_A(kk)                                                        \
    { const float* p = gA + (kk) * 32;                                    \
      *(float4*)(raf + 0)  = *(const float4*)(p + 0);                     \
      *(float4*)(raf + 4)  = *(const float4*)(p + 4);                     \
      *(float4*)(raf + 8)  = *(const float4*)(p + 8);                     \
      *(float4*)(raf + 12) = *(const float4*)(p + 12); }
#define LOAD_B(kk)                                                        \
    { const ushort* p = gB + (kk) * 32;                                   \
      *(u16x8*)(rbf + 0) = *(const u16x8*)(p + 0);                        \
      *(u16x8*)(rbf + 8) = *(const u16x8*)(p + 8); }

    LOAD_A(0); LOAD_B(0);
    const int nk = II / 32;
    for (int kk = 0; kk < nk; ++kk) {
        __syncthreads();
        alignas(16) ushort cv[16];
#pragma unroll
        for (int j = 0; j < 16; ++j) cv[j] = f2bf(raf[j]);
        *(u16x8*)(sA + 0) = *(u16x8*)(cv + 0);
        *(u16x8*)(sA + 8) = *(u16x8*)(cv + 8);
        *(u16x8*)(sB + 0) = *(u16x8*)(rbf + 0);
        *(u16x8*)(sB + 8) = *(u16x8*)(rbf + 8);
        __syncthreads();
        if (kk + 1 < nk) { LOAD_A(kk + 1); LOAD_B(kk + 1); }
        u16x8 af[4], bfr[4];
#pragma unroll
        for (int i = 0; i < 4; ++i) {
            af[i]  = *(const u16x8*)&As[(wm + i * 16 + l15) * 40 + l4 * 8];
            bfr[i] = *(const u16x8*)&Bs[(wn + i * 16 + l15) * 40 + l4 * 8];
        }
#pragma unroll
        for (int mi = 0; mi < 4; ++mi)
#pragma unroll
            for (int ni = 0; ni < 4; ++ni)
                acc[mi][ni] = mfma_bf16(af[mi], bfr[ni], acc[mi][ni]);
    }
#undef LOAD_A
#undef LOAD_B

#pragma unroll
    for (int mi = 0; mi < 4; ++mi) {
#pragma unroll
        for (int ni = 0; ni < 4; ++ni) {
            const int row = bm + wm + mi * 16 + l4 * 4;
            const int col = bn + wn + ni * 16 + l15;
            const float bsum = bih[col] + bhh[col];
#pragma unroll
            for (int r = 0; r < 4; ++r)
                xp[(size_t)(row + r) * G4 + col] = f2bf(acc[mi][ni][r] + bsum);
        }
    }
}

// ---------------------------------------------------------------- output GEMM
__global__ __launch_bounds__(256)
void gemm_out(const ushort* __restrict__ hsC, const ushort* __restrict__ Wout,
              const float* __restrict__ bout, float* __restrict__ out,
              int lgTc, int t0) {
    __shared__ ushort As[128 * 40];
    __shared__ ushort Bs[128 * 40];
    const int tid  = threadIdx.x;
    const int lane = tid & 63, wave = tid >> 6;
    const int wm = (wave >> 1) * 64, wn = (wave & 1) * 64;
    const int bn = blockIdx.x * 128;
    const int bm = blockIdx.y * 128;
    const int l15 = lane & 15, l4 = lane >> 4;

    const int srow = tid >> 1, shalf = tid & 1;
    const ushort* gA = hsC  + (size_t)(bm + srow) * HH + shalf * 16;
    const ushort* gB = Wout + (size_t)(bn + srow) * HH + shalf * 16;
    ushort* sA = &As[srow * 40 + shalf * 16];
    ushort* sB = &Bs[srow * 40 + shalf * 16];

    f32x4 acc[4][4] = {};
    u16x8 ra0 = *(const u16x8*)(gA + 0), ra1 = *(const u16x8*)(gA + 8);
    u16x8 rb0 = *(const u16x8*)(gB + 0), rb1 = *(const u16x8*)(gB + 8);

    const int nk = HH / 32;
    for (int kk = 0; kk < nk; ++kk) {
        __syncthreads();
        *(u16x8*)(sA + 0) = ra0; *(u16x8*)(sA + 8) = ra1;
        *(u16x8*)(sB + 0) = rb0; *(u16x8*)(sB + 8) = rb1;
        __syncthreads();
        if (kk + 1 < nk) {
            const ushort* pa = gA + (kk + 1) * 32;
            const ushort* pb = gB + (kk + 1) * 32;
            ra0 = *(const u16x8*)(pa + 0); ra1 = *(const u16x8*)(pa + 8);
            rb0 = *(const u16x8*)(pb + 0); rb1 = *(const u16x8*)(pb + 8);
        }
        u16x8 af[4], bfr[4];
#pragma unroll
        for (int i = 0; i < 4; ++i) {
            af[i]  = *(const u16x8*)&As[(wm + i * 16 + l15) * 40 + l4 * 8];
            bfr[i] = *(const u16x8*)&Bs[(wn + i * 16 + l15) * 40 + l4 * 8];
        }
#pragma unroll
        for (int mi = 0; mi < 4; ++mi)
#pragma unroll
            for (int ni = 0; ni < 4; ++ni)
                acc[mi][ni] = mfma_bf16(af[mi], bfr[ni], acc[mi][ni]);
    }

    const int Tcm1 = (1 << lgTc) - 1;
#pragma unroll
    for (int mi = 0; mi < 4; ++mi) {
#pragma unroll
        for (int ni = 0; ni < 4; ++ni) {
            const int row = bm + wm + mi * 16 + l4 * 4;
            const int col = bn + wn + ni * 16 + l15;
            const float bs = bout[col];
#pragma unroll
            for (int r = 0; r < 4; ++r) {
                const int rl = row + r;
                const int bIdx = rl >> lgTc, tl = rl & Tcm1;
                out[((size_t)bIdx * TT + t0 + tl) * OO + col] = acc[mi][ni][r] + bs;
            }
        }
    }
}

// ---------------------------------------------------------------- persistent scan
// 256 blocks = 4 batch-groups (16 batches) x 64 j-slices (16 cols x 4 gates).
// Whh fragments in registers. h exchange: hpack LDS merge -> lane-exclusive
// dwordx4 sc0/sc1 stores through MALL (round-6-proven). Per-group barrier =
// 64 per-block monotone flag words. xp preacts prefetched one step ahead.
__global__ __launch_bounds__(256, 1)
void lstm_scan(const ushort* __restrict__ Whh,  // [4096,1024] bf16
               const ushort* __restrict__ xp,   // [B*Tc,4096] bf16 (biases folded)
               ushort* __restrict__ hsC,        // [B*Tc,1024] bf16
               ushort* __restrict__ hbuf,       // [2][64*1024] bf16 ping-pong (MALL)
               float* __restrict__ cst,         // [64*1024] fp32
               unsigned* __restrict__ bar,      // [4][64] flags (dwords)
               int Tc, int t0) {
    __shared__ ushort HsB[16 * 1024];            // 32 KB staged h slab (swizzled)
    alignas(16) __shared__ ushort hpack[16][16]; // 512 B packed h output
    const int tid  = threadIdx.x;
    const int lane = tid & 63, wave = tid >> 6;
    const int l15 = lane & 15, l4 = lane >> 4;
    const int g = l15 >> 2, jj = l15 & 3;
    const int bg = blockIdx.x >> 6, js = blockIdx.x & 63;
    const int j0 = js * 16;

    // ---- Whh fragments -> registers (one time, plain cached loads)
    u16x8 bfr[32];
    {
        const ushort* gB = Whh +
            (size_t)(g * HH + j0 + wave * 4 + jj) * HH + l4 * 8;
#pragma unroll
        for (int kk = 0; kk < 32; ++kk)
            bfr[kk] = *(const u16x8*)(gB + kk * 32);
    }

    const int bglob = bg * 16 + l4 * 4;        // + r
    const int jcol  = j0 + wave * 4 + jj;      // this lane's hidden column
    const int srow  = tid >> 4, ss = tid & 15; // staging map: 16 rows x 16 threads

    float cr[4];
    if (t0 > 0) {
#pragma unroll
        for (int r = 0; r < 4; ++r) cr[r] = cst[(size_t)(bglob + r) * HH + jcol];
    } else {
#pragma unroll
        for (int r = 0; r < 4; ++r) cr[r] = 0.f;
    }

    // per-thread xp base: addr(r, tl) = xpT + r*Tc*G4 + tl*G4
    const ushort* xpT = xp + (size_t)bglob * Tc * G4 + g * HH + jcol;

    // prologue: prefetch xp preacts for tl = 0
    unsigned short xgn[4];
#pragma unroll
    for (int r = 0; r < 4; ++r)
        xgn[r] = xpT[(size_t)r * Tc * G4];

    for (int tl = 0; tl < Tc; ++tl) {
        const int t = t0 + tl;

        f32x4 ac0 = {}, ac1 = {};
        if (t > 0) {
            // ---- cooperative slab load: 32 KB via 8x dwordx4 sc1 per thread
            const char* hb = (const char*)hbuf +
                ((size_t)((t - 1) & 1) * (BB * HH) + (size_t)(bg * 16 + srow) * HH) * 2
                + ss * 16;
            u32x4 hv[8];
            asm volatile("global_load_dwordx4 %0, %1, off sc0 sc1"
                         : "=&v"(hv[0]) : "v"(hb) : "memory");
            asm volatile("global_load_dwordx4 %0, %1, off offset:256 sc0 sc1"
                         : "=&v"(hv[1]) : "v"(hb) : "memory");
            asm volatile("global_load_dwordx4 %0, %1, off offset:512 sc0 sc1"
                         : "=&v"(hv[2]) : "v"(hb) : "memory");
            asm volatile("global_load_dwordx4 %0, %1, off offset:768 sc0 sc1"
                         : "=&v"(hv[3]) : "v"(hb) : "memory");
            asm volatile("global_load_dwordx4 %0, %1, off offset:1024 sc0 sc1"
                         : "=&v"(hv[4]) : "v"(hb) : "memory");
            asm volatile("global_load_dwordx4 %0, %1, off offset:1280 sc0 sc1"
                         : "=&v"(hv[5]) : "v"(hb) : "memory");
            asm volatile("global_load_dwordx4 %0, %1, off offset:1536 sc0 sc1"
                         : "=&v"(hv[6]) : "v"(hb) : "memory");
            asm volatile("global_load_dwordx4 %0, %1, off offset:1792 sc0 sc1"
                         : "=&v"(hv[7]) : "v"(hb) : "memory");
            asm volatile("s_waitcnt vmcnt(0)" ::: "memory");
            __builtin_amdgcn_sched_barrier(0);
            // LDS stage with XOR swizzle (chunk ^= row&7): <=2-way conflicts
#pragma unroll
            for (int k = 0; k < 8; ++k)
                *(u16x8*)&HsB[srow * 1024 + (((ss + 16 * k) ^ (srow & 7)) * 8)] =
                    __builtin_bit_cast(u16x8, hv[k]);
            __syncthreads();
        }

        // consume previous prefetch; issue prefetch for tl+1 (hides under MFMA)
        unsigned short xgc[4];
#pragma unroll
        for (int r = 0; r < 4; ++r) xgc[r] = xgn[r];
        {
            const int tnext = (tl + 1 < Tc) ? tl + 1 : tl;
#pragma unroll
            for (int r = 0; r < 4; ++r)
                xgn[r] = xpT[(size_t)r * Tc * G4 + (size_t)tnext * G4];
        }

        if (t > 0) {
            // ---- MFMA over K=1024, B-fragments already in registers
#pragma unroll
            for (int kk = 0; kk < 32; ++kk) {
                u16x8 a = *(const u16x8*)
                    &HsB[l15 * 1024 + (((l4 + 4 * kk) ^ (l15 & 7)) * 8)];
                if (kk & 1) ac1 = mfma_bf16(a, bfr[kk], ac1);
                else        ac0 = mfma_bf16(a, bfr[kk], ac0);
            }
        }

        // per-lane preact (own gate), gather all 4 gates via shuffles
        f32x4 s;
#pragma unroll
        for (int r = 0; r < 4; ++r) s[r] = ac0[r] + ac1[r] + bf2f(xgc[r]);

        float pre[4][4];
#pragma unroll
        for (int gp = 0; gp < 4; ++gp) {
            const int src = (l4 << 4) + gp * 4 + jj;
#pragma unroll
            for (int r = 0; r < 4; ++r) pre[gp][r] = __shfl(s[r], src, 64);
        }

        unsigned short hnew[4];
#pragma unroll
        for (int r = 0; r < 4; ++r) {
            float ig = sigm(pre[0][r]);
            float fg = sigm(pre[1][r]);
            float gv = tanh_f(pre[2][r]);
            float og = sigm(pre[3][r]);
            float cn = fg * cr[r] + ig * gv;
            cr[r] = cn;
            hnew[r] = f2bf(og * tanh_f(cn));
        }

        if (g == 0) {
#pragma unroll
            for (int r = 0; r < 4; ++r) hpack[l4 * 4 + r][wave * 4 + jj] = hnew[r];
        }
        __syncthreads();

        // lane-exclusive 16B h stores through MALL (round-6-proven path)
        u32x4 lo, hi;
        if (tid < 16) {
            lo = *(const u32x4*)&hpack[tid][0];
            hi = *(const u32x4*)&hpack[tid][8];
            char* hw = (char*)hbuf +
                ((size_t)(t & 1) * (BB * HH) + (size_t)(bg * 16 + tid) * HH + j0) * 2;
            asm volatile("global_store_dwordx4 %0, %1, off sc0 sc1"
                         :: "v"(hw), "v"(lo) : "memory");
            asm volatile("global_store_dwordx4 %0, %1, off offset:16 sc0 sc1"
                         :: "v"(hw), "v"(hi) : "memory");
        }

        if (tl + 1 < Tc) {
            asm volatile("s_waitcnt vmcnt(0)" ::: "memory");
            __syncthreads();                     // all h stores drained
            if (tid == 0) {
                unsigned* fl = bar + bg * 64 + js;
                unsigned v = (unsigned)(tl + 1);
                asm volatile("global_store_dword %0, %1, off sc0 sc1"
                             :: "v"(fl), "v"(v) : "memory");
            }
        }

        // history stores (plain, off the sync critical path)
        if (tid < 16) {
            u32x4* hc = (u32x4*)&hsC[((size_t)(bg * 16 + tid) * Tc + tl) * HH + j0];
            hc[0] = lo; hc[1] = hi;
        }

        if (tl + 1 < Tc) {
            if (wave == 0) {                     // 16 lanes poll 64 flags
                const u32x4* fb = (const u32x4*)(bar + bg * 64) + l15;
                for (;;) {
                    u32x4 f;
                    asm volatile("global_load_dwordx4 %0, %1, off sc0 sc1\n\t"
                                 "s_waitcnt vmcnt(0)"
                                 : "=&v"(f) : "v"(fb) : "memory");
                    unsigned m = f[0] < f[1] ? f[0] : f[1];
                    m = m < f[2] ? m : f[2];
                    m = m < f[3] ? m : f[3];
                    bool rdy = (lane < 16) ? (m > (unsigned)tl) : true;
                    if (__all(rdy)) break;
                    __builtin_amdgcn_s_sleep(1);
                }
            }
            __syncthreads();
        }
    }

    if (g == 0) {
#pragma unroll
        for (int r = 0; r < 4; ++r) cst[(size_t)(bglob + r) * HH + jcol] = cr[r];
    }
}

// ---------------------------------------------------------------- launch
extern "C" void kernel_launch(void* const* d_in, const int* in_sizes, int n_in,
                              void* d_out, int out_size, void* d_ws, size_t ws_size,
                              hipStream_t stream) {
    const float* seq  = (const float*)d_in[0];
    const float* Wih  = (const float*)d_in[1];
    const float* Whh  = (const float*)d_in[2];
    const float* bih  = (const float*)d_in[3];
    const float* bhh  = (const float*)d_in[4];
    const float* Wout = (const float*)d_in[5];
    const float* bout = (const float*)d_in[6];

    constexpr size_t MB = 1u << 20;
    char* ws = (char*)d_ws;
    ushort*   wih_bf  = (ushort*)(ws);                       // 4 MB
    ushort*   whh_bf  = (ushort*)(ws + 4 * MB);              // 8 MB
    ushort*   wout_bf = (ushort*)(ws + 12 * MB);             // 1 MB
    float*    cst     = (float*) (ws + 13 * MB);             // 256 KB
    ushort*   hbuf    = (ushort*)(ws + 13 * MB + 262144);    // 256 KB ping-pong
    unsigned* bar     = (unsigned*)(ws + 13 * MB + 524288);  // 1 KB flags
    char*     dynbase = ws + 14 * MB;

    int Tc = 512, lg = 9;
    while (Tc > 16) {
        size_t need = 14 * MB + (size_t)Tc * BB * (size_t)(G4 + HH) * 2;
        if (need <= ws_size) break;
        Tc >>= 1; --lg;
    }
    ushort* xpb = (ushort*)dynbase;
    ushort* hsC = (ushort*)(dynbase + (size_t)Tc * BB * G4 * 2);

    auto cvt = [&](const float* in, ushort* o, int n) {
        int n4 = n / 4;
        hipLaunchKernelGGL(cvt4, dim3((n4 + 255) / 256), dim3(256), 0, stream,
                           (const float4*)in, (ushort4*)o, n4);
    };
    cvt(Wih,  wih_bf,  G4 * II);
    cvt(Whh,  whh_bf,  G4 * HH);
    cvt(Wout, wout_bf, OO * HH);

    const int Mloc = BB * Tc;
    for (int t0 = 0; t0 < TT; t0 += Tc) {
        hipLaunchKernelGGL(gemm_xproj, dim3(G4 / 128, Mloc / 128), dim3(256), 0, stream,
                           seq, wih_bf, bih, bhh, xpb, lg, t0);

        (void)hipMemsetAsync(bar, 0, 1024, stream);   // fresh barrier flags

        const ushort* whh_c = whh_bf;
        const ushort* xp_c  = xpb;
        int t0v = t0, Tcv = Tc;
        void* args[] = { (void*)&whh_c, (void*)&xp_c, (void*)&hsC, (void*)&hbuf,
                         (void*)&cst, (void*)&bar, (void*)&Tcv, (void*)&t0v };
        (void)hipLaunchCooperativeKernel((const void*)lstm_scan, dim3(256), dim3(256),
                                         args, 0, stream);

        hipLaunchKernelGGL(gemm_out, dim3(OO / 128, Mloc / 128), dim3(256), 0, stream,
                           hsC, wout_bf, bout, (float*)d_out, lg, t0);
    }
}

// Round 11
// 3098.031 us; speedup vs baseline: 13.1733x; 1.0547x over previous
//
#include <hip/hip_runtime.h>

#define DI __device__ __forceinline__

using f32x4  = __attribute__((ext_vector_type(4))) float;
using u16x8  = __attribute__((ext_vector_type(8))) unsigned short;
using u32x4  = __attribute__((ext_vector_type(4))) unsigned int;
using bf16x8 = __attribute__((ext_vector_type(8))) __bf16;

constexpr int BB = 64;    // batch
constexpr int TT = 512;   // time
constexpr int II = 512;   // input dim
constexpr int HH = 1024;  // hidden
constexpr int G4 = 4096;  // 4*H
constexpr int OO = 512;   // output dim

DI unsigned short f2bf(float f) {
    unsigned int u = __builtin_bit_cast(unsigned int, f);
    u += 0x7fffu + ((u >> 16) & 1u);   // RNE
    return (unsigned short)(u >> 16);
}
DI float bf2f(unsigned short h) {
    unsigned int u = ((unsigned int)h) << 16;
    return __builtin_bit_cast(float, u);
}
DI f32x4 mfma_bf16(u16x8 a, u16x8 b, f32x4 c) {
    return __builtin_amdgcn_mfma_f32_16x16x32_bf16(
        __builtin_bit_cast(bf16x8, a), __builtin_bit_cast(bf16x8, b), c, 0, 0, 0);
}
DI float sigm(float x) { return 1.f / (1.f + __expf(-x)); }
DI float tanh_f(float x) { return 2.f / (1.f + __expf(-2.f * x)) - 1.f; }

// ---------------------------------------------------------------- cvt fp32->bf16
__global__ __launch_bounds__(256) void cvt4(const float4* __restrict__ in,
                                            ushort4* __restrict__ out, int n4) {
    int i = blockIdx.x * 256 + threadIdx.x;
    if (i < n4) {
        float4 v = in[i];
        ushort4 o;
        o.x = f2bf(v.x); o.y = f2bf(v.y); o.z = f2bf(v.z); o.w = f2bf(v.w);
        out[i] = o;
    }
}

// ---------------------------------------------------------------- xproj GEMM
__global__ __launch_bounds__(256)
void gemm_xproj(const float* __restrict__ seq, const ushort* __restrict__ Wih,
                const float* __restrict__ bih, const float* __restrict__ bhh,
                ushort* __restrict__ xp, int lgTc, int t0) {
    __shared__ ushort As[128 * 40];
    __shared__ ushort Bs[128 * 40];
    const int tid  = threadIdx.x;
    const int lane = tid & 63, wave = tid >> 6;
    const int wm = (wave >> 1) * 64, wn = (wave & 1) * 64;
    const int bn = blockIdx.x * 128;
    const int bm = blockIdx.y * 128;
    const int l15 = lane & 15, l4 = lane >> 4;

    const int srow = tid >> 1, shalf = tid & 1;
    const int rloc = bm + srow;
    const int bIdx = rloc >> lgTc, tl = rloc & ((1 << lgTc) - 1);
    const float*  gA = seq + ((size_t)bIdx * TT + t0 + tl) * II + shalf * 16;
    const ushort* gB = Wih + (size_t)(bn + srow) * II + shalf * 16;
    ushort* sA = &As[srow * 40 + shalf * 16];
    ushort* sB = &Bs[srow * 40 + shalf * 16];

    f32x4 acc[4][4] = {};
    alignas(16) float  raf[16];
    alignas(16) ushort rbf[16];

#define LOAD_A(kk)                                                        \
    { const float* p = gA + (kk) * 32;                                    \
      *(float4*)(raf + 0)  = *(const float4*)(p + 0);                     \
      *(float4*)(raf + 4)  = *(const float4*)(p + 4);                     \
      *(float4*)(raf + 8)  = *(const float4*)(p + 8);                     \
      *(float4*)(raf + 12) = *(const float4*)(p + 12); }
#define LOAD_B(kk)                                                        \
    { const ushort* p = gB + (kk) * 32;                                   \
      *(u16x8*)(rbf + 0) = *(const u16x8*)(p + 0);                        \
      *(u16x8*)(rbf + 8) = *(const u16x8*)(p + 8); }

    LOAD_A(0); LOAD_B(0);
    const int nk = II / 32;
    for (int kk = 0; kk < nk; ++kk) {
        __syncthreads();
        alignas(16) ushort cv[16];
#pragma unroll
        for (int j = 0; j < 16; ++j) cv[j] = f2bf(raf[j]);
        *(u16x8*)(sA + 0) = *(u16x8*)(cv + 0);
        *(u16x8*)(sA + 8) = *(u16x8*)(cv + 8);
        *(u16x8*)(sB + 0) = *(u16x8*)(rbf + 0);
        *(u16x8*)(sB + 8) = *(u16x8*)(rbf + 8);
        __syncthreads();
        if (kk + 1 < nk) { LOAD_A(kk + 1); LOAD_B(kk + 1); }
        u16x8 af[4], bfr[4];
#pragma unroll
        for (int i = 0; i < 4; ++i) {
            af[i]  = *(const u16x8*)&As[(wm + i * 16 + l15) * 40 + l4 * 8];
            bfr[i] = *(const u16x8*)&Bs[(wn + i * 16 + l15) * 40 + l4 * 8];
        }
#pragma unroll
        for (int mi = 0; mi < 4; ++mi)
#pragma unroll
            for (int ni = 0; ni < 4; ++ni)
                acc[mi][ni] = mfma_bf16(af[mi], bfr[ni], acc[mi][ni]);
    }
#undef LOAD_A
#undef LOAD_B

#pragma unroll
    for (int mi = 0; mi < 4; ++mi) {
#pragma unroll
        for (int ni = 0; ni < 4; ++ni) {
            const int row = bm + wm + mi * 16 + l4 * 4;
            const int col = bn + wn + ni * 16 + l15;
            const float bsum = bih[col] + bhh[col];
#pragma unroll
            for (int r = 0; r < 4; ++r)
                xp[(size_t)(row + r) * G4 + col] = f2bf(acc[mi][ni][r] + bsum);
        }
    }
}

// ---------------------------------------------------------------- output GEMM
__global__ __launch_bounds__(256)
void gemm_out(const ushort* __restrict__ hsC, const ushort* __restrict__ Wout,
              const float* __restrict__ bout, float* __restrict__ out,
              int lgTc, int t0) {
    __shared__ ushort As[128 * 40];
    __shared__ ushort Bs[128 * 40];
    const int tid  = threadIdx.x;
    const int lane = tid & 63, wave = tid >> 6;
    const int wm = (wave >> 1) * 64, wn = (wave & 1) * 64;
    const int bn = blockIdx.x * 128;
    const int bm = blockIdx.y * 128;
    const int l15 = lane & 15, l4 = lane >> 4;

    const int srow = tid >> 1, shalf = tid & 1;
    const ushort* gA = hsC  + (size_t)(bm + srow) * HH + shalf * 16;
    const ushort* gB = Wout + (size_t)(bn + srow) * HH + shalf * 16;
    ushort* sA = &As[srow * 40 + shalf * 16];
    ushort* sB = &Bs[srow * 40 + shalf * 16];

    f32x4 acc[4][4] = {};
    u16x8 ra0 = *(const u16x8*)(gA + 0), ra1 = *(const u16x8*)(gA + 8);
    u16x8 rb0 = *(const u16x8*)(gB + 0), rb1 = *(const u16x8*)(gB + 8);

    const int nk = HH / 32;
    for (int kk = 0; kk < nk; ++kk) {
        __syncthreads();
        *(u16x8*)(sA + 0) = ra0; *(u16x8*)(sA + 8) = ra1;
        *(u16x8*)(sB + 0) = rb0; *(u16x8*)(sB + 8) = rb1;
        __syncthreads();
        if (kk + 1 < nk) {
            const ushort* pa = gA + (kk + 1) * 32;
            const ushort* pb = gB + (kk + 1) * 32;
            ra0 = *(const u16x8*)(pa + 0); ra1 = *(const u16x8*)(pa + 8);
            rb0 = *(const u16x8*)(pb + 0); rb1 = *(const u16x8*)(pb + 8);
        }
        u16x8 af[4], bfr[4];
#pragma unroll
        for (int i = 0; i < 4; ++i) {
            af[i]  = *(const u16x8*)&As[(wm + i * 16 + l15) * 40 + l4 * 8];
            bfr[i] = *(const u16x8*)&Bs[(wn + i * 16 + l15) * 40 + l4 * 8];
        }
#pragma unroll
        for (int mi = 0; mi < 4; ++mi)
#pragma unroll
            for (int ni = 0; ni < 4; ++ni)
                acc[mi][ni] = mfma_bf16(af[mi], bfr[ni], acc[mi][ni]);
    }

    const int Tcm1 = (1 << lgTc) - 1;
#pragma unroll
    for (int mi = 0; mi < 4; ++mi) {
#pragma unroll
        for (int ni = 0; ni < 4; ++ni) {
            const int row = bm + wm + mi * 16 + l4 * 4;
            const int col = bn + wn + ni * 16 + l15;
            const float bs = bout[col];
#pragma unroll
            for (int r = 0; r < 4; ++r) {
                const int rl = row + r;
                const int bIdx = rl >> lgTc, tl = rl & Tcm1;
                out[((size_t)bIdx * TT + t0 + tl) * OO + col] = acc[mi][ni][r] + bs;
            }
        }
    }
}

// ---------------------------------------------------------------- persistent scan
// 256 blocks = 4 batch-groups (16 batches) x 64 j-slices (16 cols x 4 gates).
// Whh fragments in registers. h exchange: hpack LDS merge -> lane-exclusive
// dwordx4 sc0/sc1 stores through MALL (round-6/8-proven). Per-group barrier =
// 64 per-block monotone flag words. Drain+flag are wave-0-internal (2 syncs/step).
__global__ __launch_bounds__(256, 1)
void lstm_scan(const ushort* __restrict__ Whh,  // [4096,1024] bf16
               const ushort* __restrict__ xp,   // [B*Tc,4096] bf16 (biases folded)
               ushort* __restrict__ hsC,        // [B*Tc,1024] bf16
               ushort* __restrict__ hbuf,       // [2][64*1024] bf16 ping-pong (MALL)
               float* __restrict__ cst,         // [64*1024] fp32
               unsigned* __restrict__ bar,      // [4][64] flags (dwords)
               int Tc, int t0) {
    __shared__ ushort HsB[16 * 1024];            // 32 KB staged h slab (swizzled)
    alignas(16) __shared__ ushort hpack[16][16]; // 512 B packed h output
    const int tid  = threadIdx.x;
    const int lane = tid & 63, wave = tid >> 6;
    const int l15 = lane & 15, l4 = lane >> 4;
    const int g = l15 >> 2, jj = l15 & 3;
    const int bg = blockIdx.x >> 6, js = blockIdx.x & 63;
    const int j0 = js * 16;

    // ---- Whh fragments -> registers (one time, plain cached loads)
    u16x8 bfr[32];
    {
        const ushort* gB = Whh +
            (size_t)(g * HH + j0 + wave * 4 + jj) * HH + l4 * 8;
#pragma unroll
        for (int kk = 0; kk < 32; ++kk)
            bfr[kk] = *(const u16x8*)(gB + kk * 32);
    }

    const int bglob = bg * 16 + l4 * 4;        // + r
    const int jcol  = j0 + wave * 4 + jj;      // this lane's hidden column
    const int srow  = tid >> 4, ss = tid & 15; // staging map: 16 rows x 16 threads

    float cr[4];
    if (t0 > 0) {
#pragma unroll
        for (int r = 0; r < 4; ++r) cr[r] = cst[(size_t)(bglob + r) * HH + jcol];
    } else {
#pragma unroll
        for (int r = 0; r < 4; ++r) cr[r] = 0.f;
    }

    // per-thread xp base: addr(r, tl) = xpT + r*Tc*G4 + tl*G4
    const ushort* xpT = xp + (size_t)bglob * Tc * G4 + g * HH + jcol;

    // prologue: prefetch xp preacts for tl = 0 (non-temporal: streaming)
    unsigned short xgn[4];
#pragma unroll
    for (int r = 0; r < 4; ++r)
        xgn[r] = __builtin_nontemporal_load(&xpT[(size_t)r * Tc * G4]);

    for (int tl = 0; tl < Tc; ++tl) {
        const int t = t0 + tl;

        f32x4 ac0 = {}, ac1 = {};
        if (t > 0) {
            // ---- cooperative slab load: 32 KB via 8x dwordx4 sc1 per thread
            const char* hb = (const char*)hbuf +
                ((size_t)((t - 1) & 1) * (BB * HH) + (size_t)(bg * 16 + srow) * HH) * 2
                + ss * 16;
            u32x4 hv[8];
            asm volatile("global_load_dwordx4 %0, %1, off sc0 sc1"
                         : "=&v"(hv[0]) : "v"(hb) : "memory");
            asm volatile("global_load_dwordx4 %0, %1, off offset:256 sc0 sc1"
                         : "=&v"(hv[1]) : "v"(hb) : "memory");
            asm volatile("global_load_dwordx4 %0, %1, off offset:512 sc0 sc1"
                         : "=&v"(hv[2]) : "v"(hb) : "memory");
            asm volatile("global_load_dwordx4 %0, %1, off offset:768 sc0 sc1"
                         : "=&v"(hv[3]) : "v"(hb) : "memory");
            asm volatile("global_load_dwordx4 %0, %1, off offset:1024 sc0 sc1"
                         : "=&v"(hv[4]) : "v"(hb) : "memory");
            asm volatile("global_load_dwordx4 %0, %1, off offset:1280 sc0 sc1"
                         : "=&v"(hv[5]) : "v"(hb) : "memory");
            asm volatile("global_load_dwordx4 %0, %1, off offset:1536 sc0 sc1"
                         : "=&v"(hv[6]) : "v"(hb) : "memory");
            asm volatile("global_load_dwordx4 %0, %1, off offset:1792 sc0 sc1"
                         : "=&v"(hv[7]) : "v"(hb) : "memory");
            asm volatile("s_waitcnt vmcnt(0)" ::: "memory");
            __builtin_amdgcn_sched_barrier(0);
            // LDS stage with XOR swizzle (chunk ^= row&7): <=2-way conflicts
#pragma unroll
            for (int k = 0; k < 8; ++k)
                *(u16x8*)&HsB[srow * 1024 + (((ss + 16 * k) ^ (srow & 7)) * 8)] =
                    __builtin_bit_cast(u16x8, hv[k]);
            __syncthreads();
        }

        // consume previous prefetch; issue prefetch for tl+1 (hides under MFMA)
        unsigned short xgc[4];
#pragma unroll
        for (int r = 0; r < 4; ++r) xgc[r] = xgn[r];
        {
            const size_t tn = (size_t)((tl + 1 < Tc) ? tl + 1 : tl) * G4;
#pragma unroll
            for (int r = 0; r < 4; ++r)
                xgn[r] = __builtin_nontemporal_load(&xpT[(size_t)r * Tc * G4 + tn]);
        }

        if (t > 0) {
            // ---- MFMA over K=1024, B-fragments already in registers
#pragma unroll
            for (int kk = 0; kk < 32; ++kk) {
                u16x8 a = *(const u16x8*)
                    &HsB[l15 * 1024 + (((l4 + 4 * kk) ^ (l15 & 7)) * 8)];
                if (kk & 1) ac1 = mfma_bf16(a, bfr[kk], ac1);
                else        ac0 = mfma_bf16(a, bfr[kk], ac0);
            }
        }

        // per-lane preact (own gate), gather all 4 gates via shuffles
        f32x4 s;
#pragma unroll
        for (int r = 0; r < 4; ++r) s[r] = ac0[r] + ac1[r] + bf2f(xgc[r]);

        float pre[4][4];
#pragma unroll
        for (int gp = 0; gp < 4; ++gp) {
            const int src = (l4 << 4) + gp * 4 + jj;
#pragma unroll
            for (int r = 0; r < 4; ++r) pre[gp][r] = __shfl(s[r], src, 64);
        }

        unsigned short hnew[4];
#pragma unroll
        for (int r = 0; r < 4; ++r) {
            float ig = sigm(pre[0][r]);
            float fg = sigm(pre[1][r]);
            float gv = tanh_f(pre[2][r]);
            float og = sigm(pre[3][r]);
            float cn = fg * cr[r] + ig * gv;
            cr[r] = cn;
            hnew[r] = f2bf(og * tanh_f(cn));
        }

        if (g == 0) {
#pragma unroll
            for (int r = 0; r < 4; ++r) hpack[l4 * 4 + r][wave * 4 + jj] = hnew[r];
        }
        __syncthreads();

        // wave-0-internal publish: stores -> wave-0 vmcnt drain -> flag.
        // (exchange chain identical to round 8; only the cross-wave sync removed,
        //  which the chain never needed: all h stores and the flag are in wave 0)
        u32x4 lo, hi;
        if (wave == 0) {
            if (tid < 16) {
                lo = *(const u32x4*)&hpack[tid][0];
                hi = *(const u32x4*)&hpack[tid][8];
                char* hw = (char*)hbuf +
                    ((size_t)(t & 1) * (BB * HH) + (size_t)(bg * 16 + tid) * HH + j0) * 2;
                asm volatile("global_store_dwordx4 %0, %1, off sc0 sc1"
                             :: "v"(hw), "v"(lo) : "memory");
                asm volatile("global_store_dwordx4 %0, %1, off offset:16 sc0 sc1"
                             :: "v"(hw), "v"(hi) : "memory");
            }
            if (tl + 1 < Tc) {
                asm volatile("s_waitcnt vmcnt(0)" ::: "memory");
                if (tid == 0) {
                    unsigned* fl = bar + bg * 64 + js;
                    unsigned v = (unsigned)(tl + 1);
                    asm volatile("global_store_dword %0, %1, off sc0 sc1"
                                 :: "v"(fl), "v"(v) : "memory");
                }
            }
        }

        // history stores (non-temporal, off the sync critical path)
        if (tid < 16) {
            u32x4* hc = (u32x4*)&hsC[((size_t)(bg * 16 + tid) * Tc + tl) * HH + j0];
            __builtin_nontemporal_store(lo, hc);
            __builtin_nontemporal_store(hi, hc + 1);
        }

        if (tl + 1 < Tc) {
            if (wave == 0) {                     // 16 lanes poll 64 flags
                const u32x4* fb = (const u32x4*)(bar + bg * 64) + l15;
                for (;;) {
                    u32x4 f;
                    asm volatile("global_load_dwordx4 %0, %1, off sc0 sc1\n\t"
                                 "s_waitcnt vmcnt(0)"
                                 : "=&v"(f) : "v"(fb) : "memory");
                    unsigned m = f[0] < f[1] ? f[0] : f[1];
                    m = m < f[2] ? m : f[2];
                    m = m < f[3] ? m : f[3];
                    bool rdy = (lane < 16) ? (m > (unsigned)tl) : true;
                    if (__all(rdy)) break;
                    __builtin_amdgcn_s_sleep(1);
                }
            }
            __syncthreads();
        }
    }

    if (g == 0) {
#pragma unroll
        for (int r = 0; r < 4; ++r) cst[(size_t)(bglob + r) * HH + jcol] = cr[r];
    }
}

// ---------------------------------------------------------------- launch
extern "C" void kernel_launch(void* const* d_in, const int* in_sizes, int n_in,
                              void* d_out, int out_size, void* d_ws, size_t ws_size,
                              hipStream_t stream) {
    const float* seq  = (const float*)d_in[0];
    const float* Wih  = (const float*)d_in[1];
    const float* Whh  = (const float*)d_in[2];
    const float* bih  = (const float*)d_in[3];
    const float* bhh  = (const float*)d_in[4];
    const float* Wout = (const float*)d_in[5];
    const float* bout = (const float*)d_in[6];

    constexpr size_t MB = 1u << 20;
    char* ws = (char*)d_ws;
    ushort*   wih_bf  = (ushort*)(ws);                       // 4 MB
    ushort*   whh_bf  = (ushort*)(ws + 4 * MB);              // 8 MB
    ushort*   wout_bf = (ushort*)(ws + 12 * MB);             // 1 MB
    float*    cst     = (float*) (ws + 13 * MB);             // 256 KB
    ushort*   hbuf    = (ushort*)(ws + 13 * MB + 262144);    // 256 KB ping-pong
    unsigned* bar     = (unsigned*)(ws + 13 * MB + 524288);  // 1 KB flags
    char*     dynbase = ws + 14 * MB;

    int Tc = 512, lg = 9;
    while (Tc > 16) {
        size_t need = 14 * MB + (size_t)Tc * BB * (size_t)(G4 + HH) * 2;
        if (need <= ws_size) break;
        Tc >>= 1; --lg;
    }
    ushort* xpb = (ushort*)dynbase;
    ushort* hsC = (ushort*)(dynbase + (size_t)Tc * BB * G4 * 2);

    auto cvt = [&](const float* in, ushort* o, int n) {
        int n4 = n / 4;
        hipLaunchKernelGGL(cvt4, dim3((n4 + 255) / 256), dim3(256), 0, stream,
                           (const float4*)in, (ushort4*)o, n4);
    };
    cvt(Wih,  wih_bf,  G4 * II);
    cvt(Whh,  whh_bf,  G4 * HH);
    cvt(Wout, wout_bf, OO * HH);

    const int Mloc = BB * Tc;
    for (int t0 = 0; t0 < TT; t0 += Tc) {
        hipLaunchKernelGGL(gemm_xproj, dim3(G4 / 128, Mloc / 128), dim3(256), 0, stream,
                           seq, wih_bf, bih, bhh, xpb, lg, t0);

        (void)hipMemsetAsync(bar, 0, 1024, stream);   // fresh barrier flags

        const ushort* whh_c = whh_bf;
        const ushort* xp_c  = xpb;
        int t0v = t0, Tcv = Tc;
        void* args[] = { (void*)&whh_c, (void*)&xp_c, (void*)&hsC, (void*)&hbuf,
                         (void*)&cst, (void*)&bar, (void*)&Tcv, (void*)&t0v };
        (void)hipLaunchCooperativeKernel((const void*)lstm_scan, dim3(256), dim3(256),
                                         args, 0, stream);

        hipLaunchKernelGGL(gemm_out, dim3(OO / 128, Mloc / 128), dim3(256), 0, stream,
                           hsC, wout_bf, bout, (float*)d_out, lg, t0);
    }
}